// Round 6
// baseline (346.063 us; speedup 1.0000x reference)
//
#include <hip/hip_runtime.h>
#include <hip/hip_bf16.h>

constexpr int NB   = 2;
constexpr int LL   = 512;
constexpr int LLP  = 516;          // padded s_exp row stride (kills 4-way b128 conflicts)
constexpr int FF   = 128;
constexpr int CC   = 64;
constexpr int HH   = 12;
constexpr int DD   = 16;
constexpr int HD   = HH * DD;      // 192
constexpr int FEAT = HH*CC + HH*DD + HH*7;  // 1044
constexpr float INFV   = 100000.0f;
constexpr float SCALEF = 0.57735026918962576f;   // sqrt(1/3)
constexpr float SQ29H  = 0.23570226039551584f;   // sqrt(2/9)/2

// ---------------- kernel 0: active-row compaction ----------------
__global__ void compact_kernel(const int* __restrict__ maskg, int* __restrict__ row_map)
{
    const int tid = threadIdx.x;               // 1024 threads = NB*LL
    const int lane = tid & 63, wv = tid >> 6;  // 16 waves
    __shared__ int s_cnt[16];
    __shared__ int s_off[16];
    __shared__ int s_tot;
    const int m = maskg[tid] ? 1 : 0;
    unsigned long long b = __ballot(m);
    const int pre = __popcll(b & ((1ull << lane) - 1ull));
    if (lane == 0) s_cnt[wv] = __popcll(b);
    __syncthreads();
    if (tid == 0) {
        int s = 0;
        for (int w = 0; w < 16; ++w) { s_off[w] = s; s += s_cnt[w]; }
        s_tot = s;
    }
    __syncthreads();
    const int nact = s_off[wv] + pre;          // actives strictly before tid
    if (m) row_map[nact] = tid;
    else   row_map[s_tot + (tid - nact)] = tid;
}

// ---------------- kernel 1: q/k/v projections, 4 rows per block ----------------
__global__ __launch_bounds__(192) void qkv_kernel(
    const float* __restrict__ xg, const float* __restrict__ Wq,
    const float* __restrict__ Wk, const float* __restrict__ Wv,
    float* __restrict__ q_ws, float* __restrict__ kT4, float* __restrict__ vT)
{
    const int b = blockIdx.x;          // 256 blocks, rows b*4 .. b*4+3 (never straddle n)
    const int t = threadIdx.x;         // 192
    __shared__ __align__(16) float sx[4*FF];
    __shared__ __align__(16) float sw[3*HD*20];   // 45 KB

    for (int o = t; o < 4*FF; o += 192) sx[o] = xg[(size_t)b*4*FF + o];

    float aq[4] = {0.f,0.f,0.f,0.f};
    float ak[4] = {0.f,0.f,0.f,0.f};
    float av[4] = {0.f,0.f,0.f,0.f};

    for (int ft = 0; ft < 8; ++ft) {
        __syncthreads();
        #pragma unroll
        for (int m = 0; m < 3; ++m) {
            const float* W = (m == 0) ? Wq : ((m == 1) ? Wk : Wv);
            #pragma unroll
            for (int p = 0; p < 4; ++p) {
                const int r = (t >> 2) + 48*p, q = t & 3;
                float4 v = *(const float4*)(W + (size_t)r*FF + ft*16 + q*4);
                *(float4*)&sw[m*3840 + r*20 + q*4] = v;
            }
        }
        __syncthreads();
        const float* wq = &sw[0*3840 + t*20];
        const float* wk = &sw[1*3840 + t*20];
        const float* wv = &sw[2*3840 + t*20];
        #pragma unroll
        for (int f4 = 0; f4 < 4; ++f4) {
            float4 a  = *(const float4*)&wq[f4*4];
            float4 bq = *(const float4*)&wk[f4*4];
            float4 cq = *(const float4*)&wv[f4*4];
            #pragma unroll
            for (int r = 0; r < 4; ++r) {
                float4 xv = *(const float4*)&sx[r*FF + ft*16 + f4*4];   // broadcast
                aq[r] += xv.x*a.x  + xv.y*a.y  + xv.z*a.z  + xv.w*a.w;
                ak[r] += xv.x*bq.x + xv.y*bq.y + xv.z*bq.z + xv.w*bq.w;
                av[r] += xv.x*cq.x + xv.y*cq.y + xv.z*cq.z + xv.w*cq.w;
            }
        }
    }
    const int n = (b*4) >> 9, i0 = (b*4) & 511;
    #pragma unroll
    for (int r = 0; r < 4; ++r) {
        const int row = b*4 + r, i = i0 + r;
        q_ws[(size_t)row*HD + t] = aq[r];
        kT4[(((size_t)n*48 + (t >> 2))*LL + i)*4 + (t & 3)] = ak[r];
    }
    *(float4*)&vT[((size_t)n*HD + t)*LL + i0] = make_float4(av[0], av[1], av[2], av[3]);
}

// ---------------- kernel 2: fused attention (LDS-issue-pipe optimized) ----------------
// r6 vs r5: cut LDS instruction count (one LDS unit/CU, b128 ~12cy each was
// ~16us/block serialized):
//  - P1: q via uniform pointer (s_load path), s_q deleted       (-384 b128/blk)
//  - 2a: exp 8-j reg slices reused over 16 v rows + butterflies (-360 b128/blk)
//  - wave7: sums+aggr via reg slices + butterflies              (~-1000 instr/blk)
//  - P4: s_f k-slice in regs (5 b128) reused over 16 f/wave;
//        Wout reads 1KB/instr coalesced; butterfly per f        (-480 b128/blk)
__global__ __launch_bounds__(512, 2) void attn_kernel(
    const float* __restrict__ Rg, const float* __restrict__ tg, const float* __restrict__ pg,
    const float* __restrict__ xg, const float* __restrict__ zg, const int* __restrict__ maskg,
    const float* __restrict__ Wpbg, const float* __restrict__ gammag,
    const float* __restrict__ Woutg, const float* __restrict__ boutg,
    const float* __restrict__ lnwg, const float* __restrict__ lnbg,
    const float* __restrict__ q_ws, const float* __restrict__ kT4, const float* __restrict__ vT,
    const int* __restrict__ row_map, float* __restrict__ outg)
{
    const int row = row_map[blockIdx.x];  // load-balanced: active rows first
    const int n = row >> 9;
    const int tid = threadIdx.x;

    __shared__ __align__(16) float s_exp[HH*LLP];  // 24.2 KB  exp(logits), h-major, padded
    __shared__ __align__(16) float s_big[4*768];   // 12 KB  2b partials
    __shared__ __align__(16) float s_p[3*LL];      // 6 KB   p_CB for this n
    __shared__ __align__(16) float s_x[FF];
    __shared__ __align__(16) float s_y[FF];
    __shared__ __align__(16) float s_f[1280];      // 5 KB   FEAT=1044, zero-padded for P4
    __shared__ float s_aggr[36];
    __shared__ float s_inv[HH];
    __shared__ float s_coef[HH];
    __shared__ float s_geo[15];   // p_i[3], t[3], R[9]
    __shared__ float s_red[2];

    if (tid < FF) s_x[tid] = xg[(size_t)row*FF + tid];
    if (tid < 236) s_f[1044 + tid] = 0.f;          // P4 pad
    for (int o = tid; o < 3*LL; o += 512) s_p[o] = pg[(size_t)n*3*LL + o];
    if (tid >= 320 && tid < 332) {
        float g = gammag[tid-320];
        float gamma = log1pf(__expf(fminf(g, 80.0f)));   // softplus
        s_coef[tid-320] = -gamma * SQ29H;
    }
    if (tid >= 332 && tid < 335) s_geo[tid-332] = pg[(size_t)row*3 + (tid-332)];
    if (tid >= 335 && tid < 338) s_geo[3 + tid-335] = tg[(size_t)row*3 + (tid-335)];
    if (tid >= 338 && tid < 347) s_geo[6 + tid-338] = Rg[(size_t)row*9 + (tid-338)];
    const int mi = maskg[row];   // block-uniform
    __syncthreads();

    if (mi) {
        // ---- phase 1: exp(logits), one j per thread; Wpb & q via scalar loads ----
        {
            const int j = tid;
            float acc[HH];

            // z row -> 16 float4 regs, then FMA vs uniform (SGPR) Wpb
            const float* zr = zg + ((size_t)row*LL + j)*CC;
            float4 zv[16];
            #pragma unroll
            for (int c4 = 0; c4 < 16; ++c4) zv[c4] = ((const float4*)zr)[c4];
            #pragma unroll
            for (int h = 0; h < HH; ++h) {
                const float4* wh = (const float4*)(Wpbg + h*CC);   // block-uniform -> s_load
                float a = 0.f;
                #pragma unroll
                for (int c4 = 0; c4 < 16; ++c4) {
                    float4 w = wh[c4];
                    a += zv[c4].x*w.x + zv[c4].y*w.y + zv[c4].z*w.z + zv[c4].w*w.w;
                }
                acc[h] = a;
            }
            // q . k : q block-uniform -> scalar loads; k 8 loads in flight
            const float* qp = q_ws + (size_t)row*HD;               // uniform
            const float* kb = kT4 + ((size_t)(n*48)*LL + j)*4;
            #pragma unroll
            for (int g = 0; g < 6; ++g) {
                float4 kv[8];
                #pragma unroll
                for (int u = 0; u < 8; ++u)
                    kv[u] = *(const float4*)(kb + (size_t)(g*8+u)*LL*4);
                #pragma unroll
                for (int u = 0; u < 8; ++u) {
                    const int hd4 = g*8+u;
                    float4 q4v = *(const float4*)(qp + hd4*4);     // uniform -> s_load
                    acc[hd4 >> 2] += q4v.x*kv[u].x + q4v.y*kv[u].y + q4v.z*kv[u].z + q4v.w*kv[u].w;
                }
            }
            float e0 = s_geo[0]-s_p[j*3+0];
            float e1 = s_geo[1]-s_p[j*3+1];
            float e2 = s_geo[2]-s_p[j*3+2];
            float d2 = e0*e0 + e1*e1 + e2*e2;
            const float sub = maskg[n*LL + j] ? 0.0f : INFV;
            #pragma unroll
            for (int h = 0; h < HH; ++h) {
                float lg = (acc[h] + d2*s_coef[h]) * SCALEF - sub;
                s_exp[h*LLP + j] = __expf(fminf(lg, 80.0f));
            }
        }
        __syncthreads();

        // ---- phase 2: 2b / 2a / (sums + aggr) concurrent on disjoint waves ----
        {
            const int wv = tid >> 6, lane = tid & 63;
            if (wv < 4) {
                // 2b: feat_p2n partials; 16 z loads in flight, float4 ep broadcasts
                const int c = lane, q4v = wv;
                float acc[HH];
                #pragma unroll
                for (int h = 0; h < HH; ++h) acc[h] = 0.f;
                const float* zb = zg + ((size_t)row*LL + q4v*128)*CC + c;
                const float* ep = s_exp + q4v*128;
                for (int jj = 0; jj < 128; jj += 16) {
                    float zr16[16];
                    #pragma unroll
                    for (int u = 0; u < 16; ++u) zr16[u] = zb[(size_t)(jj+u)*CC];
                    #pragma unroll
                    for (int h = 0; h < HH; ++h) {
                        float4 e0 = *(const float4*)&ep[h*LLP + jj];
                        float4 e1 = *(const float4*)&ep[h*LLP + jj + 4];
                        float4 e2 = *(const float4*)&ep[h*LLP + jj + 8];
                        float4 e3 = *(const float4*)&ep[h*LLP + jj + 12];
                        acc[h] += e0.x*zr16[0] + e0.y*zr16[1] + e0.z*zr16[2] + e0.w*zr16[3]
                                + e1.x*zr16[4] + e1.y*zr16[5] + e1.z*zr16[6] + e1.w*zr16[7]
                                + e2.x*zr16[8] + e2.y*zr16[9] + e2.z*zr16[10]+ e2.w*zr16[11]
                                + e3.x*zr16[12]+ e3.y*zr16[13]+ e3.z*zr16[14]+ e3.w*zr16[15];
                    }
                }
                #pragma unroll
                for (int h = 0; h < HH; ++h) s_big[q4v*768 + h*64 + c] = acc[h];
            } else if (tid < 448) {
                // 2a: feat_node; per h keep 8-j exp slice in regs, reuse over 16 rows
                const int w = wv - 4;              // 0..2
                for (int hh = 0; hh < 4; ++hh) {
                    const int h = w*4 + hh;
                    const float* ep = s_exp + h*LLP + lane*8;
                    float4 ea = *(const float4*)ep;
                    float4 eb = *(const float4*)(ep + 4);
                    const float* vb = vT + ((size_t)n*HD + h*16)*LL + lane*8;
                    for (int d = 0; d < 16; ++d) {
                        const float* vp = vb + (size_t)d*LL;
                        float4 va = *(const float4*)vp;
                        float4 v2 = *(const float4*)(vp + 4);
                        float a = ea.x*va.x + ea.y*va.y + ea.z*va.z + ea.w*va.w
                                + eb.x*v2.x + eb.y*v2.y + eb.z*v2.z + eb.w*v2.w;
                        #pragma unroll
                        for (int off = 32; off > 0; off >>= 1) a += __shfl_xor(a, off, 64);
                        if (lane == 0) s_f[768 + h*16 + d] = a;   // raw; scaled in P3
                    }
                }
            } else {
                // wave 7: per-head sums + raw aggr, 8-j reg slices + butterflies
                float pp[24];
                #pragma unroll
                for (int u = 0; u < 6; ++u)
                    *(float4*)&pp[u*4] = *(const float4*)&s_p[lane*24 + u*4];
                for (int h = 0; h < HH; ++h) {
                    const float* ep = s_exp + h*LLP + lane*8;
                    float4 ea = *(const float4*)ep;
                    float4 eb = *(const float4*)(ep + 4);
                    float s  = ea.x+ea.y+ea.z+ea.w + eb.x+eb.y+eb.z+eb.w;
                    float a0 = ea.x*pp[0] + ea.y*pp[3] + ea.z*pp[6]  + ea.w*pp[9]
                             + eb.x*pp[12]+ eb.y*pp[15]+ eb.z*pp[18] + eb.w*pp[21];
                    float a1 = ea.x*pp[1] + ea.y*pp[4] + ea.z*pp[7]  + ea.w*pp[10]
                             + eb.x*pp[13]+ eb.y*pp[16]+ eb.z*pp[19] + eb.w*pp[22];
                    float a2 = ea.x*pp[2] + ea.y*pp[5] + ea.z*pp[8]  + ea.w*pp[11]
                             + eb.x*pp[14]+ eb.y*pp[17]+ eb.z*pp[20] + eb.w*pp[23];
                    #pragma unroll
                    for (int off = 32; off > 0; off >>= 1) {
                        s  += __shfl_xor(s,  off, 64);
                        a0 += __shfl_xor(a0, off, 64);
                        a1 += __shfl_xor(a1, off, 64);
                        a2 += __shfl_xor(a2, off, 64);
                    }
                    if (lane == 0) {
                        s_inv[h] = 1.0f / fmaxf(s, 1e-30f);
                        s_aggr[h*3+0] = a0; s_aggr[h*3+1] = a1; s_aggr[h*3+2] = a2;
                    }
                }
            }
        }
        __syncthreads();

        // ---- phase 3: apply s_inv + spatial features ----
        for (int o = tid; o < 960; o += 512) {
            if (o < 768)
                s_f[o] = (s_big[o] + s_big[768+o] + s_big[1536+o] + s_big[2304+o]) * s_inv[o >> 6];
            else
                s_f[o] = s_f[o] * s_inv[(o - 768) >> 4];
        }
        if (tid >= 500) {
            const int h = tid - 500;   // 0..11
            const float iv = s_inv[h];
            float m0 = s_aggr[h*3+0]*iv - s_geo[3];
            float m1 = s_aggr[h*3+1]*iv - s_geo[4];
            float m2 = s_aggr[h*3+2]*iv - s_geo[5];
            const float* Rm = &s_geo[6];           // local_i = sum_j R[j][i]*m[j]
            float l0 = Rm[0]*m0 + Rm[3]*m1 + Rm[6]*m2;
            float l1 = Rm[1]*m0 + Rm[4]*m1 + Rm[7]*m2;
            float l2 = Rm[2]*m0 + Rm[5]*m1 + Rm[8]*m2;
            float dist = sqrtf(l0*l0 + l1*l1 + l2*l2);
            float idn = 1.0f/(dist + 1e-4f);
            s_f[960 + h*3+0] = l0; s_f[960 + h*3+1] = l1; s_f[960 + h*3+2] = l2;
            s_f[996 + h] = dist;
            s_f[1008 + h*3+0] = l0*idn; s_f[1008 + h*3+1] = l1*idn; s_f[1008 + h*3+2] = l2*idn;
        }
        __syncthreads();

        // ---- phase 4: output projection; s_f k-slice in regs, 16 f per wave ----
        {
            const int wv = tid >> 6, lane = tid & 63;
            float4 sf[5];
            #pragma unroll
            for (int u = 0; u < 5; ++u) sf[u] = *(const float4*)&s_f[(lane + 64*u)*4];
            const int f0 = wv*16;
            for (int fi = 0; fi < 16; ++fi) {
                const int f = f0 + fi;
                const float* wr = Woutg + (size_t)f * FEAT;
                float acc = 0.f;
                #pragma unroll
                for (int u = 0; u < 5; ++u) {
                    const int k4 = lane + 64*u;
                    if (k4 < 261) {
                        float4 w4 = *(const float4*)(wr + k4*4);
                        acc += sf[u].x*w4.x + sf[u].y*w4.y + sf[u].z*w4.z + sf[u].w*w4.w;
                    }
                }
                #pragma unroll
                for (int off = 32; off > 0; off >>= 1) acc += __shfl_xor(acc, off, 64);
                if (lane == 0) s_y[f] = s_x[f] + boutg[f] + acc;
            }
        }
    } else {
        if (tid < FF) s_y[tid] = s_x[tid];
    }
    __syncthreads();

    // ---- LayerNorm ----
    if (tid < 64) {
        float a = s_y[tid], b = s_y[tid + 64];
        float s1 = a + b, s2 = a*a + b*b;
        #pragma unroll
        for (int off = 32; off > 0; off >>= 1) {
            s1 += __shfl_xor(s1, off, 64);
            s2 += __shfl_xor(s2, off, 64);
        }
        if (tid == 0) { s_red[0] = s1; s_red[1] = s2; }
    }
    __syncthreads();
    if (tid < FF) {
        float mu  = s_red[0] * (1.0f/FF);
        float var = s_red[1] * (1.0f/FF) - mu*mu;
        float vv = (s_y[tid] - mu) * rsqrtf(fmaxf(var, 0.0f) + 1e-5f);
        vv = vv * lnwg[tid] + lnbg[tid];
        outg[(size_t)row*FF + tid] = vv;
    }
}

extern "C" void kernel_launch(void* const* d_in, const int* in_sizes, int n_in,
                              void* d_out, int out_size, void* d_ws, size_t ws_size,
                              hipStream_t stream) {
    const float* Rg    = (const float*)d_in[0];
    const float* tg    = (const float*)d_in[1];
    const float* pg    = (const float*)d_in[2];
    const float* xg    = (const float*)d_in[3];
    const float* zg    = (const float*)d_in[4];
    const int*   maskg = (const int*)d_in[5];
    const float* Wq    = (const float*)d_in[6];
    const float* Wk    = (const float*)d_in[7];
    const float* Wv    = (const float*)d_in[8];
    const float* Wpb   = (const float*)d_in[9];
    const float* gam   = (const float*)d_in[10];
    const float* Wout  = (const float*)d_in[11];
    const float* bout  = (const float*)d_in[12];
    const float* lnw   = (const float*)d_in[13];
    const float* lnb   = (const float*)d_in[14];
    float* outp = (float*)d_out;

    float* q_ws = (float*)d_ws;
    float* kT4  = q_ws + (size_t)NB*LL*HD;
    float* vT   = kT4  + (size_t)NB*LL*HD;
    int*   row_map = (int*)(vT + (size_t)NB*LL*HD);

    compact_kernel<<<1, NB*LL, 0, stream>>>(maskg, row_map);
    qkv_kernel<<<NB*LL/4, HD, 0, stream>>>(xg, Wq, Wk, Wv, q_ws, kT4, vT);
    attn_kernel<<<NB*LL, 512, 0, stream>>>(Rg, tg, pg, xg, zg, maskg,
                                           Wpb, gam, Wout, bout, lnw, lnb,
                                           q_ws, kT4, vT, row_map, outp);
}

// Round 7
// 265.749 us; speedup vs baseline: 1.3022x; 1.3022x over previous
//
#include <hip/hip_runtime.h>
#include <hip/hip_bf16.h>

constexpr int NB   = 2;
constexpr int LL   = 512;
constexpr int LLP  = 516;          // padded s_exp row stride (kills 4-way b128 conflicts)
constexpr int FF   = 128;
constexpr int CC   = 64;
constexpr int HH   = 12;
constexpr int DD   = 16;
constexpr int HD   = HH * DD;      // 192
constexpr int FEAT = HH*CC + HH*DD + HH*7;  // 1044
constexpr float INFV   = 100000.0f;
constexpr float SCALEF = 0.57735026918962576f;   // sqrt(1/3)
constexpr float SQ29H  = 0.23570226039551584f;   // sqrt(2/9)/2

// ---------------- kernel 0: active-row compaction ----------------
__global__ void compact_kernel(const int* __restrict__ maskg, int* __restrict__ row_map)
{
    const int tid = threadIdx.x;               // 1024 threads = NB*LL
    const int lane = tid & 63, wv = tid >> 6;  // 16 waves
    __shared__ int s_cnt[16];
    __shared__ int s_off[16];
    __shared__ int s_tot;
    const int m = maskg[tid] ? 1 : 0;
    unsigned long long b = __ballot(m);
    const int pre = __popcll(b & ((1ull << lane) - 1ull));
    if (lane == 0) s_cnt[wv] = __popcll(b);
    __syncthreads();
    if (tid == 0) {
        int s = 0;
        for (int w = 0; w < 16; ++w) { s_off[w] = s; s += s_cnt[w]; }
        s_tot = s;
    }
    __syncthreads();
    const int nact = s_off[wv] + pre;          // actives strictly before tid
    if (m) row_map[nact] = tid;
    else   row_map[s_tot + (tid - nact)] = tid;
}

// ---------------- kernel 1: q/k/v projections, 4 rows per block ----------------
__global__ __launch_bounds__(192) void qkv_kernel(
    const float* __restrict__ xg, const float* __restrict__ Wq,
    const float* __restrict__ Wk, const float* __restrict__ Wv,
    float* __restrict__ q_ws, float* __restrict__ kT4, float* __restrict__ vT)
{
    const int b = blockIdx.x;          // 256 blocks, rows b*4 .. b*4+3 (never straddle n)
    const int t = threadIdx.x;         // 192
    __shared__ __align__(16) float sx[4*FF];
    __shared__ __align__(16) float sw[3*HD*20];   // 45 KB

    for (int o = t; o < 4*FF; o += 192) sx[o] = xg[(size_t)b*4*FF + o];

    float aq[4] = {0.f,0.f,0.f,0.f};
    float ak[4] = {0.f,0.f,0.f,0.f};
    float av[4] = {0.f,0.f,0.f,0.f};

    for (int ft = 0; ft < 8; ++ft) {
        __syncthreads();
        #pragma unroll
        for (int m = 0; m < 3; ++m) {
            const float* W = (m == 0) ? Wq : ((m == 1) ? Wk : Wv);
            #pragma unroll
            for (int p = 0; p < 4; ++p) {
                const int r = (t >> 2) + 48*p, q = t & 3;
                float4 v = *(const float4*)(W + (size_t)r*FF + ft*16 + q*4);
                *(float4*)&sw[m*3840 + r*20 + q*4] = v;
            }
        }
        __syncthreads();
        const float* wq = &sw[0*3840 + t*20];
        const float* wk = &sw[1*3840 + t*20];
        const float* wv = &sw[2*3840 + t*20];
        #pragma unroll
        for (int f4 = 0; f4 < 4; ++f4) {
            float4 a  = *(const float4*)&wq[f4*4];
            float4 bq = *(const float4*)&wk[f4*4];
            float4 cq = *(const float4*)&wv[f4*4];
            #pragma unroll
            for (int r = 0; r < 4; ++r) {
                float4 xv = *(const float4*)&sx[r*FF + ft*16 + f4*4];   // broadcast
                aq[r] += xv.x*a.x  + xv.y*a.y  + xv.z*a.z  + xv.w*a.w;
                ak[r] += xv.x*bq.x + xv.y*bq.y + xv.z*bq.z + xv.w*bq.w;
                av[r] += xv.x*cq.x + xv.y*cq.y + xv.z*cq.z + xv.w*cq.w;
            }
        }
    }
    const int n = (b*4) >> 9, i0 = (b*4) & 511;
    #pragma unroll
    for (int r = 0; r < 4; ++r) {
        const int row = b*4 + r, i = i0 + r;
        q_ws[(size_t)row*HD + t] = aq[r];
        kT4[(((size_t)n*48 + (t >> 2))*LL + i)*4 + (t & 3)] = ak[r];
    }
    *(float4*)&vT[((size_t)n*HD + t)*LL + i0] = make_float4(av[0], av[1], av[2], av[3]);
}

// ---------------- kernel 2: fused attention (r5 structure) ----------------
// r7 vs r5 (r6 reverted — its 64-lane butterflies are ds_swizzle = LDS pipe):
//  - 2b: 8-deep software pipeline; first z-batch issued BEFORE the post-P1
//    barrier (loads independent of s_exp) -> hides LLC latency
//  - wave7 aggr: ep read as float4 (128 b128 instead of 512 b32)
__global__ __launch_bounds__(512, 2) void attn_kernel(
    const float* __restrict__ Rg, const float* __restrict__ tg, const float* __restrict__ pg,
    const float* __restrict__ xg, const float* __restrict__ zg, const int* __restrict__ maskg,
    const float* __restrict__ Wpbg, const float* __restrict__ gammag,
    const float* __restrict__ Woutg, const float* __restrict__ boutg,
    const float* __restrict__ lnwg, const float* __restrict__ lnbg,
    const float* __restrict__ q_ws, const float* __restrict__ kT4, const float* __restrict__ vT,
    const int* __restrict__ row_map, float* __restrict__ outg)
{
    const int row = row_map[blockIdx.x];  // load-balanced: active rows first
    const int n = row >> 9;
    const int tid = threadIdx.x;

    __shared__ __align__(16) float s_exp[HH*LLP];  // 24.2 KB  exp(logits), h-major, padded
    __shared__ __align__(16) float s_big[4*768];   // 12 KB  2b partials
    __shared__ __align__(16) float s_p[3*LL];      // 6 KB   p_CB for this n
    __shared__ __align__(16) float s_q[HD];
    __shared__ __align__(16) float s_x[FF];
    __shared__ __align__(16) float s_y[FF];
    __shared__ __align__(16) float s_f[FEAT];
    __shared__ float s_aggr[36];
    __shared__ float s_inv[HH];
    __shared__ float s_coef[HH];
    __shared__ float s_geo[15];   // p_i[3], t[3], R[9]
    __shared__ float s_red[2];

    if (tid < FF) s_x[tid] = xg[(size_t)row*FF + tid];
    if (tid >= 128 && tid < 128 + HD) s_q[tid-128] = q_ws[(size_t)row*HD + (tid-128)];
    for (int o = tid; o < 3*LL; o += 512) s_p[o] = pg[(size_t)n*3*LL + o];
    if (tid >= 320 && tid < 332) {
        float g = gammag[tid-320];
        float gamma = log1pf(__expf(fminf(g, 80.0f)));   // softplus
        s_coef[tid-320] = -gamma * SQ29H;
    }
    if (tid >= 332 && tid < 335) s_geo[tid-332] = pg[(size_t)row*3 + (tid-332)];
    if (tid >= 335 && tid < 338) s_geo[3 + tid-335] = tg[(size_t)row*3 + (tid-335)];
    if (tid >= 338 && tid < 347) s_geo[6 + tid-338] = Rg[(size_t)row*9 + (tid-338)];
    const int mi = maskg[row];   // block-uniform
    __syncthreads();

    if (mi) {
        float zc[8];   // 2b pipeline registers (waves 0-3), live across barrier

        // ---- phase 1: exp(logits), one j per thread; Wpb via scalar loads ----
        {
            const int j = tid;
            float acc[HH];

            // z row -> 16 float4 regs, then FMA vs uniform (SGPR) Wpb
            const float* zr = zg + ((size_t)row*LL + j)*CC;
            float4 zv[16];
            #pragma unroll
            for (int c4 = 0; c4 < 16; ++c4) zv[c4] = ((const float4*)zr)[c4];
            #pragma unroll
            for (int h = 0; h < HH; ++h) {
                const float4* wh = (const float4*)(Wpbg + h*CC);   // block-uniform -> s_load
                float a = 0.f;
                #pragma unroll
                for (int c4 = 0; c4 < 16; ++c4) {
                    float4 w = wh[c4];
                    a += zv[c4].x*w.x + zv[c4].y*w.y + zv[c4].z*w.z + zv[c4].w*w.w;
                }
                acc[h] = a;
            }
            // q . k : kT4, 8 loads in flight per group
            const float* kb = kT4 + ((size_t)(n*48)*LL + j)*4;
            #pragma unroll
            for (int g = 0; g < 6; ++g) {
                float4 kv[8];
                #pragma unroll
                for (int u = 0; u < 8; ++u)
                    kv[u] = *(const float4*)(kb + (size_t)(g*8+u)*LL*4);
                #pragma unroll
                for (int u = 0; u < 8; ++u) {
                    const int hd4 = g*8+u;
                    float4 q4v = *(const float4*)&s_q[hd4*4];
                    acc[hd4 >> 2] += q4v.x*kv[u].x + q4v.y*kv[u].y + q4v.z*kv[u].z + q4v.w*kv[u].w;
                }
            }
            float e0 = s_geo[0]-s_p[j*3+0];
            float e1 = s_geo[1]-s_p[j*3+1];
            float e2 = s_geo[2]-s_p[j*3+2];
            float d2 = e0*e0 + e1*e1 + e2*e2;
            const float sub = maskg[n*LL + j] ? 0.0f : INFV;
            #pragma unroll
            for (int h = 0; h < HH; ++h) {
                float lg = (acc[h] + d2*s_coef[h]) * SCALEF - sub;
                s_exp[h*LLP + j] = __expf(fminf(lg, 80.0f));
            }
        }

        // ---- prefetch first 2b z-batch across the barrier (waves 0-3) ----
        if (tid < 256) {
            const int wv0 = tid >> 6, lane0 = tid & 63;
            const float* zb = zg + ((size_t)row*LL + wv0*128)*CC + lane0;
            #pragma unroll
            for (int u = 0; u < 8; ++u) zc[u] = zb[(size_t)u*CC];
        }
        __syncthreads();

        // ---- phase 2: 2b / 2a / (sums + aggr) concurrent on disjoint waves ----
        {
            const int wv = tid >> 6, lane = tid & 63;
            if (wv < 4) {
                // 2b: feat_p2n partials; 8-deep pipelined z loads
                const int c = lane, q4v = wv;
                float acc[HH];
                #pragma unroll
                for (int h = 0; h < HH; ++h) acc[h] = 0.f;
                const float* zb = zg + ((size_t)row*LL + q4v*128)*CC + c;
                const float* ep = s_exp + q4v*128;
                for (int jj = 0; jj < 128; jj += 8) {
                    float zn[8];
                    if (jj + 8 < 128) {
                        #pragma unroll
                        for (int u = 0; u < 8; ++u) zn[u] = zb[(size_t)(jj+8+u)*CC];
                    }
                    #pragma unroll
                    for (int h = 0; h < HH; ++h) {
                        float4 ea = *(const float4*)&ep[h*LLP + jj];
                        float4 eb = *(const float4*)&ep[h*LLP + jj + 4];
                        acc[h] += ea.x*zc[0] + ea.y*zc[1] + ea.z*zc[2] + ea.w*zc[3]
                                + eb.x*zc[4] + eb.y*zc[5] + eb.z*zc[6] + eb.w*zc[7];
                    }
                    #pragma unroll
                    for (int u = 0; u < 8; ++u) zc[u] = zn[u];
                }
                #pragma unroll
                for (int h = 0; h < HH; ++h) s_big[q4v*768 + h*64 + c] = acc[h];
            } else if (tid < 448) {
                // 2a: feat_node; 4 hd rows x 16 j-chunks per instruction (coalesced)
                const int w = (tid >> 6) - 4;      // 0..2
                const int hsub = lane >> 4;        // 0..3
                const int jj = lane & 15;          // 0..15
                const int wbase = w * 64;
                #pragma unroll 2
                for (int g = 0; g < 16; ++g) {
                    const int hd = wbase + g*4 + hsub;
                    const float* vb = vT + ((size_t)n*HD + hd)*LL;
                    const float* ep = s_exp + (hd >> 4)*LLP;
                    float a = 0.f;
                    #pragma unroll
                    for (int t8 = 0; t8 < 8; ++t8) {
                        float4 vv = *(const float4*)(vb + (jj + 16*t8)*4);
                        float4 ev = *(const float4*)(ep + (jj + 16*t8)*4);
                        a += vv.x*ev.x + vv.y*ev.y + vv.z*ev.z + vv.w*ev.w;
                    }
                    a += __shfl_xor(a, 1, 64);
                    a += __shfl_xor(a, 2, 64);
                    a += __shfl_xor(a, 4, 64);
                    a += __shfl_xor(a, 8, 64);
                    if (jj == 0) s_f[768 + hd] = a;   // raw; scaled in phase 3
                }
            } else {
                // wave 7: per-head sums first (all 64 lanes), then raw aggr
                const int o = tid - 448;
                for (int h = 0; h < HH; ++h) {
                    float s = 0.f;
                    #pragma unroll
                    for (int r = 0; r < 8; ++r) s += s_exp[h*LLP + lane + (r<<6)];
                    #pragma unroll
                    for (int off = 32; off > 0; off >>= 1) s += __shfl_xor(s, off, 64);
                    if (lane == 0) s_inv[h] = 1.0f / fmaxf(s, 1e-30f);
                }
                if (o < 36) {
                    const int h = o / 3, ax = o - h*3;
                    const float* ep = s_exp + h*LLP;
                    float a = 0.f;
                    #pragma unroll 4
                    for (int j4 = 0; j4 < 128; ++j4) {
                        float4 e4 = *(const float4*)&ep[j4*4];
                        const float* pb = &s_p[j4*12 + ax];
                        a += e4.x*pb[0] + e4.y*pb[3] + e4.z*pb[6] + e4.w*pb[9];
                    }
                    s_aggr[o] = a;   // raw; scaled in phase 3
                }
            }
        }
        __syncthreads();

        // ---- phase 3: apply s_inv + spatial features ----
        for (int o = tid; o < 960; o += 512) {
            if (o < 768)
                s_f[o] = (s_big[o] + s_big[768+o] + s_big[1536+o] + s_big[2304+o]) * s_inv[o >> 6];
            else
                s_f[o] = s_f[o] * s_inv[(o - 768) >> 4];
        }
        if (tid >= 500) {
            const int h = tid - 500;   // 0..11
            const float iv = s_inv[h];
            float m0 = s_aggr[h*3+0]*iv - s_geo[3];
            float m1 = s_aggr[h*3+1]*iv - s_geo[4];
            float m2 = s_aggr[h*3+2]*iv - s_geo[5];
            const float* Rm = &s_geo[6];           // local_i = sum_j R[j][i]*m[j]
            float l0 = Rm[0]*m0 + Rm[3]*m1 + Rm[6]*m2;
            float l1 = Rm[1]*m0 + Rm[4]*m1 + Rm[7]*m2;
            float l2 = Rm[2]*m0 + Rm[5]*m1 + Rm[8]*m2;
            float dist = sqrtf(l0*l0 + l1*l1 + l2*l2);
            float idn = 1.0f/(dist + 1e-4f);
            s_f[960 + h*3+0] = l0; s_f[960 + h*3+1] = l1; s_f[960 + h*3+2] = l2;
            s_f[996 + h] = dist;
            s_f[1008 + h*3+0] = l0*idn; s_f[1008 + h*3+1] = l1*idn; s_f[1008 + h*3+2] = l2*idn;
        }
        __syncthreads();

        // ---- phase 4: output projection; quad of lanes per f (16 lines/instr) ----
        {
            const int f = tid >> 2, q4 = tid & 3;
            const float* wr = Woutg + (size_t)f * FEAT;
            float acc = 0.f;
            #pragma unroll 4
            for (int kk = q4*4; kk < FEAT; kk += 16) {
                float4 fv  = *(const float4*)&s_f[kk];
                float4 wvv = *(const float4*)(wr + kk);
                acc += fv.x*wvv.x + fv.y*wvv.y + fv.z*wvv.z + fv.w*wvv.w;
            }
            acc += __shfl_xor(acc, 1, 64);
            acc += __shfl_xor(acc, 2, 64);
            if (q4 == 0) s_y[f] = s_x[f] + boutg[f] + acc;
        }
    } else {
        if (tid < FF) s_y[tid] = s_x[tid];
    }
    __syncthreads();

    // ---- LayerNorm ----
    if (tid < 64) {
        float a = s_y[tid], b = s_y[tid + 64];
        float s1 = a + b, s2 = a*a + b*b;
        #pragma unroll
        for (int off = 32; off > 0; off >>= 1) {
            s1 += __shfl_xor(s1, off, 64);
            s2 += __shfl_xor(s2, off, 64);
        }
        if (tid == 0) { s_red[0] = s1; s_red[1] = s2; }
    }
    __syncthreads();
    if (tid < FF) {
        float mu  = s_red[0] * (1.0f/FF);
        float var = s_red[1] * (1.0f/FF) - mu*mu;
        float vv = (s_y[tid] - mu) * rsqrtf(fmaxf(var, 0.0f) + 1e-5f);
        vv = vv * lnwg[tid] + lnbg[tid];
        outg[(size_t)row*FF + tid] = vv;
    }
}

extern "C" void kernel_launch(void* const* d_in, const int* in_sizes, int n_in,
                              void* d_out, int out_size, void* d_ws, size_t ws_size,
                              hipStream_t stream) {
    const float* Rg    = (const float*)d_in[0];
    const float* tg    = (const float*)d_in[1];
    const float* pg    = (const float*)d_in[2];
    const float* xg    = (const float*)d_in[3];
    const float* zg    = (const float*)d_in[4];
    const int*   maskg = (const int*)d_in[5];
    const float* Wq    = (const float*)d_in[6];
    const float* Wk    = (const float*)d_in[7];
    const float* Wv    = (const float*)d_in[8];
    const float* Wpb   = (const float*)d_in[9];
    const float* gam   = (const float*)d_in[10];
    const float* Wout  = (const float*)d_in[11];
    const float* bout  = (const float*)d_in[12];
    const float* lnw   = (const float*)d_in[13];
    const float* lnb   = (const float*)d_in[14];
    float* outp = (float*)d_out;

    float* q_ws = (float*)d_ws;
    float* kT4  = q_ws + (size_t)NB*LL*HD;
    float* vT   = kT4  + (size_t)NB*LL*HD;
    int*   row_map = (int*)(vT + (size_t)NB*LL*HD);

    compact_kernel<<<1, NB*LL, 0, stream>>>(maskg, row_map);
    qkv_kernel<<<NB*LL/4, HD, 0, stream>>>(xg, Wq, Wk, Wv, q_ws, kT4, vT);
    attn_kernel<<<NB*LL, 512, 0, stream>>>(Rg, tg, pg, xg, zg, maskg,
                                           Wpb, gam, Wout, bout, lnw, lnb,
                                           q_ws, kT4, vT, row_map, outp);
}